// Round 1
// baseline (168.168 us; speedup 1.0000x reference)
//
#include <hip/hip_runtime.h>
#include <math.h>

#define N_NODES 50000
#define DEG 16
#define E_EDGES (N_NODES * DEG)
#define FIN 128
#define FTOT 192   // 2*FQK + FV
#define FQK 64
#define FV 64
#define H 8

typedef __attribute__((ext_vector_type(8))) short short8;
typedef __attribute__((ext_vector_type(4))) float float4v;

__device__ inline unsigned short f2bf(float f) {
    unsigned int u = __float_as_uint(f);
    unsigned int r = u + 0x7fffu + ((u >> 16) & 1u);  // RNE
    return (unsigned short)(r >> 16);
}

#define LDC 194   // 192 + 2 bf16 pad for the epilogue transpose

// ---------- one-time W prep: fp32 [128][192] -> bf16 image Wb[n][k] = [192][128] ----------
__global__ __launch_bounds__(256) void wprep(const float* __restrict__ W,
                                             unsigned short* __restrict__ Wb) {
    const int t = blockIdx.x * 256 + threadIdx.x;   // 0..3071
    const int n = t % 192, kg = t / 192;            // kg 0..15
    unsigned short tmp[8];
#pragma unroll
    for (int j = 0; j < 8; j++)
        tmp[j] = f2bf(W[(kg * 8 + j) * FTOT + n]);  // lanes sweep n: coalesced reads
    *(uint4*)(Wb + n * FIN + kg * 8) = *(const uint4*)tmp;
}

// ---------- GEMM: qkv(bf16, kv-interleaved) = x @ W via MFMA ----------
// Block: 256 thr = 4 waves, 64 rows. B-tile comes prebuilt (bf16) from L2;
// staged into LDS with XOR swizzle so ds_read_b128 is bank-conflict-free.
__global__ __launch_bounds__(256) void gemm_qkv(const float* __restrict__ x,
                                                const unsigned short* __restrict__ Wb,
                                                unsigned short* __restrict__ qkv) {
    __shared__ unsigned short Bt[FTOT * FIN];   // 49152 B, swizzled image
    unsigned short* Ct = Bt;                    // reused after MFMAs (needs 24832 B)
    const int tid = threadIdx.x;
    const int wave = tid >> 6, lane = tid & 63;
    const int m = lane & 15, q = lane >> 4;
    const int row = blockIdx.x * 64 + wave * 16 + m;
    const int rowc = min(row, N_NODES - 1);

    // A fragments first so x-load latency hides under W staging
    short8 a[4];
    const float* xr = x + (size_t)rowc * FIN;
#pragma unroll
    for (int s = 0; s < 4; s++) {
        float4v f0 = *(const float4v*)(xr + s * 32 + q * 8);
        float4v f1 = *(const float4v*)(xr + s * 32 + q * 8 + 4);
        short8 av;
        av[0] = (short)f2bf(f0.x); av[1] = (short)f2bf(f0.y);
        av[2] = (short)f2bf(f0.z); av[3] = (short)f2bf(f0.w);
        av[4] = (short)f2bf(f1.x); av[5] = (short)f2bf(f1.y);
        av[6] = (short)f2bf(f1.z); av[7] = (short)f2bf(f1.w);
        a[s] = av;
    }

    // stage Wb -> Bt: 12 x 16B chunks/thread, coalesced global reads,
    // LDS dest chunk XOR-swizzled: c ^= (row&7)  (row = c>>4, 16 chunks/row)
#pragma unroll
    for (int i = 0; i < 12; i++) {
        const int c = i * 256 + tid;                 // chunk 0..3071
        uint4 v = *(const uint4*)(Wb + c * 8);
        const int cs = c ^ ((c >> 4) & 7);
        *(uint4*)(&Bt[cs * 8]) = v;
    }
    __syncthreads();

    float4v acc[12];
#pragma unroll
    for (int ct = 0; ct < 12; ct++) acc[ct] = (float4v){0.f, 0.f, 0.f, 0.f};
#pragma unroll
    for (int ct = 0; ct < 12; ct++) {
        const int n = ct * 16 + m;
        const int sw = (n & 7) << 4;
#pragma unroll
        for (int s = 0; s < 4; s++) {
            const short8 b = *(const short8*)((const char*)Bt +
                             (((n << 8) + s * 64 + q * 16) ^ sw));
            acc[ct] = __builtin_amdgcn_mfma_f32_16x16x32_bf16(a[s], b, acc[ct], 0, 0, 0);
        }
    }
    __syncthreads();   // all Bt reads done; safe to reuse as Ct

    // transpose into interleaved-layout LDS tile (q pre-scaled)
    const int lrow0 = wave * 16 + q * 4;
#pragma unroll
    for (int ct = 0; ct < 12; ct++) {
        const int col = ct * 16 + m;
        int off; float scale;
        if (col < FQK)          { off = col;                      scale = 0.35355339059327373f; }
        else if (col < 2 * FQK) { off = 64 + 2 * (col - 64);      scale = 1.f; }  // k
        else                    { off = 64 + 2 * (col - 128) + 1; scale = 1.f; }  // v
#pragma unroll
        for (int i = 0; i < 4; i++)
            Ct[(lrow0 + i) * LDC + off] = f2bf(acc[ct][i] * scale);
    }
    __syncthreads();

    // coalesced store: 64 rows x 96 dwords
    unsigned int* qg = (unsigned int*)qkv;
    const int base = blockIdx.x * 64;
#pragma unroll
    for (int i = 0; i < 24; i++) {
        int l = tid + i * 256;
        int r = l / 96, dw = l - r * 96;
        if (base + r < N_NODES)
            qg[(size_t)(base + r) * 96 + dw] = *(const unsigned int*)(&Ct[r * LDC + 2 * dw]);
    }
}

// ---------- attention v2: one wave per node, 4 lanes per edge ----------
// lane = 4*g + r: edge g (0..15), quarter r owns heads 2r,2r+1 (dims 16r..16r+15).
// All 16 edge gathers issue immediately (no shfl-broadcast dependency);
// q.k dot is fully lane-local; softmax + output reduce via 4-round butterflies.
__global__ __launch_bounds__(256) void attn(const unsigned short* __restrict__ qkv,
                                            const int* __restrict__ dest,
                                            float* __restrict__ out) {
    const int node = blockIdx.x * 4 + (threadIdx.x >> 6);
    const int lane = threadIdx.x & 63;
    const int g = lane >> 2;
    const int r = lane & 3;
    if (node >= N_NODES) return;   // wave-uniform

    const int d = dest[node * DEG + g];

    const unsigned short* qp = qkv + (size_t)node * FTOT + 16 * r;  // pre-scaled q
    const uint4 qv0 = *(const uint4*)(qp);
    const uint4 qv1 = *(const uint4*)(qp + 8);

    const unsigned short* kp = qkv + (size_t)d * FTOT + 64 + 32 * r;  // kv interleaved
    const uint4 kv0 = *(const uint4*)(kp);
    const uint4 kv1 = *(const uint4*)(kp + 8);
    const uint4 kv2 = *(const uint4*)(kp + 16);
    const uint4 kv3 = *(const uint4*)(kp + 24);

    const unsigned int qw[8]  = {qv0.x, qv0.y, qv0.z, qv0.w, qv1.x, qv1.y, qv1.z, qv1.w};
    const unsigned int kvw[16] = {kv0.x, kv0.y, kv0.z, kv0.w, kv1.x, kv1.y, kv1.z, kv1.w,
                                  kv2.x, kv2.y, kv2.z, kv2.w, kv3.x, kv3.y, kv3.z, kv3.w};
    // kvw[u] = { k[16r+u] (lo), v[16r+u] (hi) }

    float la = 0.f, lb = 0.f;   // logits for heads 2r, 2r+1 of edge g
#pragma unroll
    for (int f = 0; f < 8; f++) {
        const unsigned int qa = qw[f >> 1];
        const unsigned int qb = qw[(f + 8) >> 1];
        const float qfa = __uint_as_float((f & 1) ? (qa & 0xffff0000u) : (qa << 16));
        const float qfb = __uint_as_float((f & 1) ? (qb & 0xffff0000u) : (qb << 16));
        la = fmaf(qfa, __uint_as_float(kvw[f] << 16), la);
        lb = fmaf(qfb, __uint_as_float(kvw[f + 8] << 16), lb);
    }

    // per-head max over the 16 edges (lanes with equal r, xor over g-bits)
    float ma = la, mb = lb;
#pragma unroll
    for (int msk = 4; msk <= 32; msk <<= 1) {
        ma = fmaxf(ma, __shfl_xor(ma, msk, 64));
        mb = fmaxf(mb, __shfl_xor(mb, msk, 64));
    }
    const float pa = __expf(la - ma);
    const float pb = __expf(lb - mb);
    float sa = pa, sb = pb;
#pragma unroll
    for (int msk = 4; msk <= 32; msk <<= 1) {
        sa += __shfl_xor(sa, msk, 64);
        sb += __shfl_xor(sb, msk, 64);
    }

    // weighted v contribution of this edge, then distributed butterfly sum
    float o[16];
#pragma unroll
    for (int w = 0; w < 8; w++) {
        o[w]     = pa * __uint_as_float(kvw[w] & 0xffff0000u);
        o[w + 8] = pb * __uint_as_float(kvw[w + 8] & 0xffff0000u);
    }
#pragma unroll
    for (int m2 = 4, h = 8; h >= 1; m2 <<= 1, h >>= 1) {
        const bool up = (lane & m2) != 0;
#pragma unroll
        for (int j = 0; j < h; j++) {
            const float send = up ? o[j] : o[j + h];
            const float recv = __shfl_xor(send, m2, 64);
            o[j] = (up ? o[j + h] : o[j]) + recv;
        }
    }
    // lane (g,r) now holds the summed output for dim 16r + bitrev4(g)
    const int w = ((g & 1) << 3) | ((g & 2) << 1) | ((g & 4) >> 1) | ((g & 8) >> 3);
    out[(size_t)node * 64 + 16 * r + w] = o[0] / ((w < 8) ? sa : sb);
}

extern "C" void kernel_launch(void* const* d_in, const int* in_sizes, int n_in,
                              void* d_out, int out_size, void* d_ws, size_t ws_size,
                              hipStream_t stream) {
    const float* x = (const float*)d_in[0];
    const float* W = (const float*)d_in[1];
    // d_in[2] = batch (unused by reference)
    const int* ei = (const int*)d_in[3];
    const int* dest = ei + E_EDGES;  // ei[1]
    float* out = (float*)d_out;

    unsigned short* qkv = (unsigned short*)d_ws;                    // 19.2 MB
    unsigned short* Wb  = qkv + (size_t)N_NODES * FTOT;             // +48 KB bf16 W image

    wprep<<<12, 256, 0, stream>>>(W, Wb);
    gemm_qkv<<<(N_NODES + 63) / 64, 256, 0, stream>>>(x, Wb, qkv);
    attn<<<(N_NODES + 3) / 4, 256, 0, stream>>>(qkv, dest, out);
}

// Round 2
// 113.225 us; speedup vs baseline: 1.4853x; 1.4853x over previous
//
#include <hip/hip_runtime.h>
#include <math.h>

#define N_NODES 50000
#define DEG 16
#define E_EDGES (N_NODES * DEG)
#define FIN 128
#define FTOT 192   // 2*FQK + FV
#define FQK 64
#define FV 64
#define H 8

typedef __attribute__((ext_vector_type(8))) short short8;
typedef __attribute__((ext_vector_type(4))) float float4v;

__device__ inline unsigned short f2bf(float f) {
    unsigned int u = __float_as_uint(f);
    unsigned int r = u + 0x7fffu + ((u >> 16) & 1u);  // RNE
    return (unsigned short)(r >> 16);
}

#define LDC 194   // 192 + 2 bf16 pad for the epilogue transpose

// ---------- one-time W prep: fp32 [128][192] -> bf16 image Wb[n][k] = [192][128] ----------
__global__ __launch_bounds__(256) void wprep(const float* __restrict__ W,
                                             unsigned short* __restrict__ Wb) {
    const int t = blockIdx.x * 256 + threadIdx.x;   // 0..3071
    const int n = t % 192, kg = t / 192;            // kg 0..15
    unsigned short tmp[8];
#pragma unroll
    for (int j = 0; j < 8; j++)
        tmp[j] = f2bf(W[(kg * 8 + j) * FTOT + n]);  // lanes sweep n: coalesced reads
    *(uint4*)(Wb + n * FIN + kg * 8) = *(const uint4*)tmp;
}

// ---------- GEMM: qkv(bf16, kv-interleaved) = x @ W via MFMA ----------
// Block: 256 thr = 4 waves, 64 rows. B-tile comes prebuilt (bf16) from L2;
// staged into LDS with XOR swizzle so ds_read_b128 is bank-conflict-free.
__global__ __launch_bounds__(256) void gemm_qkv(const float* __restrict__ x,
                                                const unsigned short* __restrict__ Wb,
                                                unsigned short* __restrict__ qkv) {
    __shared__ unsigned short Bt[FTOT * FIN];   // 49152 B, swizzled image
    unsigned short* Ct = Bt;                    // reused after MFMAs (needs 24832 B)
    const int tid = threadIdx.x;
    const int wave = tid >> 6, lane = tid & 63;
    const int m = lane & 15, q = lane >> 4;
    const int row = blockIdx.x * 64 + wave * 16 + m;
    const int rowc = min(row, N_NODES - 1);

    // A fragments first so x-load latency hides under W staging
    short8 a[4];
    const float* xr = x + (size_t)rowc * FIN;
#pragma unroll
    for (int s = 0; s < 4; s++) {
        float4v f0 = *(const float4v*)(xr + s * 32 + q * 8);
        float4v f1 = *(const float4v*)(xr + s * 32 + q * 8 + 4);
        short8 av;
        av[0] = (short)f2bf(f0.x); av[1] = (short)f2bf(f0.y);
        av[2] = (short)f2bf(f0.z); av[3] = (short)f2bf(f0.w);
        av[4] = (short)f2bf(f1.x); av[5] = (short)f2bf(f1.y);
        av[6] = (short)f2bf(f1.z); av[7] = (short)f2bf(f1.w);
        a[s] = av;
    }

    // stage Wb -> Bt: 12 x 16B chunks/thread, coalesced global reads,
    // LDS dest chunk XOR-swizzled: c ^= (row&7)  (row = c>>4, 16 chunks/row)
#pragma unroll
    for (int i = 0; i < 12; i++) {
        const int c = i * 256 + tid;                 // chunk 0..3071
        uint4 v = *(const uint4*)(Wb + c * 8);
        const int cs = c ^ ((c >> 4) & 7);
        *(uint4*)(&Bt[cs * 8]) = v;
    }
    __syncthreads();

    float4v acc[12];
#pragma unroll
    for (int ct = 0; ct < 12; ct++) acc[ct] = (float4v){0.f, 0.f, 0.f, 0.f};
#pragma unroll
    for (int ct = 0; ct < 12; ct++) {
        const int n = ct * 16 + m;
        const int sw = (n & 7) << 4;
#pragma unroll
        for (int s = 0; s < 4; s++) {
            const short8 b = *(const short8*)((const char*)Bt +
                             (((n << 8) + s * 64 + q * 16) ^ sw));
            acc[ct] = __builtin_amdgcn_mfma_f32_16x16x32_bf16(a[s], b, acc[ct], 0, 0, 0);
        }
    }
    __syncthreads();   // all Bt reads done; safe to reuse as Ct

    // transpose into interleaved-layout LDS tile (q pre-scaled)
    const int lrow0 = wave * 16 + q * 4;
#pragma unroll
    for (int ct = 0; ct < 12; ct++) {
        const int col = ct * 16 + m;
        int off; float scale;
        if (col < FQK)          { off = col;                      scale = 0.35355339059327373f; }
        else if (col < 2 * FQK) { off = 64 + 2 * (col - 64);      scale = 1.f; }  // k
        else                    { off = 64 + 2 * (col - 128) + 1; scale = 1.f; }  // v
#pragma unroll
        for (int i = 0; i < 4; i++)
            Ct[(lrow0 + i) * LDC + off] = f2bf(acc[ct][i] * scale);
    }
    __syncthreads();

    // coalesced store: 64 rows x 96 dwords
    unsigned int* qg = (unsigned int*)qkv;
    const int base = blockIdx.x * 64;
#pragma unroll
    for (int i = 0; i < 24; i++) {
        int l = tid + i * 256;
        int r = l / 96, dw = l - r * 96;
        if (base + r < N_NODES)
            qg[(size_t)(base + r) * 96 + dw] = *(const unsigned int*)(&Ct[r * LDC + 2 * dw]);
    }
}

// ---------- attention v3: one wave per node, 4 lanes per edge, STATIC indexing ----------
// lane = 4*g + r: edge g (0..15), quarter r owns heads 2r,2r+1 (dims 16r..16r+15).
// All 16 edge gathers issue immediately; q.k dot is lane-local; softmax and output
// reduce via butterflies. All array indices compile-time (v2's runtime-h butterfly
// sent o[]/kvw[] to scratch: VGPR=28, VALUBusy=97%, 92us).
__global__ __launch_bounds__(256) void attn(const unsigned short* __restrict__ qkv,
                                            const int* __restrict__ dest,
                                            float* __restrict__ out) {
    const int node = blockIdx.x * 4 + (threadIdx.x >> 6);
    const int lane = threadIdx.x & 63;
    const int g = lane >> 2;
    const int r = lane & 3;
    if (node >= N_NODES) return;   // wave-uniform

    const int d = dest[node * DEG + g];

    const unsigned short* qp = qkv + (size_t)node * FTOT + 16 * r;  // pre-scaled q
    const uint4 qv0 = *(const uint4*)(qp);
    const uint4 qv1 = *(const uint4*)(qp + 8);

    const unsigned short* kp = qkv + (size_t)d * FTOT + 64 + 32 * r;  // kv interleaved
    const uint4 kv0 = *(const uint4*)(kp);
    const uint4 kv1 = *(const uint4*)(kp + 8);
    const uint4 kv2 = *(const uint4*)(kp + 16);
    const uint4 kv3 = *(const uint4*)(kp + 24);

    const unsigned int qw[8]  = {qv0.x, qv0.y, qv0.z, qv0.w, qv1.x, qv1.y, qv1.z, qv1.w};
    const unsigned int kvw[16] = {kv0.x, kv0.y, kv0.z, kv0.w, kv1.x, kv1.y, kv1.z, kv1.w,
                                  kv2.x, kv2.y, kv2.z, kv2.w, kv3.x, kv3.y, kv3.z, kv3.w};
    // kvw[u] = { k[16r+u] (lo), v[16r+u] (hi) }

    float la = 0.f, lb = 0.f;   // logits for heads 2r, 2r+1 of edge g
#pragma unroll
    for (int f = 0; f < 8; f++) {
        const unsigned int qa = qw[f >> 1];
        const unsigned int qb = qw[(f + 8) >> 1];
        const float qfa = __uint_as_float((f & 1) ? (qa & 0xffff0000u) : (qa << 16));
        const float qfb = __uint_as_float((f & 1) ? (qb & 0xffff0000u) : (qb << 16));
        la = fmaf(qfa, __uint_as_float(kvw[f] << 16), la);
        lb = fmaf(qfb, __uint_as_float(kvw[f + 8] << 16), lb);
    }

    // per-head max over the 16 edges (lanes with equal r, xor over g-bits)
    float ma = la, mb = lb;
    ma = fmaxf(ma, __shfl_xor(ma, 4, 64));  mb = fmaxf(mb, __shfl_xor(mb, 4, 64));
    ma = fmaxf(ma, __shfl_xor(ma, 8, 64));  mb = fmaxf(mb, __shfl_xor(mb, 8, 64));
    ma = fmaxf(ma, __shfl_xor(ma, 16, 64)); mb = fmaxf(mb, __shfl_xor(mb, 16, 64));
    ma = fmaxf(ma, __shfl_xor(ma, 32, 64)); mb = fmaxf(mb, __shfl_xor(mb, 32, 64));
    const float pa = __expf(la - ma);
    const float pb = __expf(lb - mb);
    float sa = pa, sb = pb;
    sa += __shfl_xor(sa, 4, 64);  sb += __shfl_xor(sb, 4, 64);
    sa += __shfl_xor(sa, 8, 64);  sb += __shfl_xor(sb, 8, 64);
    sa += __shfl_xor(sa, 16, 64); sb += __shfl_xor(sb, 16, 64);
    sa += __shfl_xor(sa, 32, 64); sb += __shfl_xor(sb, 32, 64);

    // weighted v contribution of this edge, then distributed butterfly sum.
    // Each round: compile-time h and m2 so every o[] index is a constant.
    float o[16];
#pragma unroll
    for (int w = 0; w < 8; w++) {
        o[w]     = pa * __uint_as_float(kvw[w] & 0xffff0000u);
        o[w + 8] = pb * __uint_as_float(kvw[w + 8] & 0xffff0000u);
    }
    {   // round 1: m2=4, h=8
        const bool up = (lane & 4) != 0;
#pragma unroll
        for (int j = 0; j < 8; j++) {
            const float send = up ? o[j] : o[j + 8];
            const float recv = __shfl_xor(send, 4, 64);
            o[j] = (up ? o[j + 8] : o[j]) + recv;
        }
    }
    {   // round 2: m2=8, h=4
        const bool up = (lane & 8) != 0;
#pragma unroll
        for (int j = 0; j < 4; j++) {
            const float send = up ? o[j] : o[j + 4];
            const float recv = __shfl_xor(send, 8, 64);
            o[j] = (up ? o[j + 4] : o[j]) + recv;
        }
    }
    {   // round 3: m2=16, h=2
        const bool up = (lane & 16) != 0;
#pragma unroll
        for (int j = 0; j < 2; j++) {
            const float send = up ? o[j] : o[j + 2];
            const float recv = __shfl_xor(send, 16, 64);
            o[j] = (up ? o[j + 2] : o[j]) + recv;
        }
    }
    {   // round 4: m2=32, h=1
        const bool up = (lane & 32) != 0;
        const float send = up ? o[0] : o[1];
        const float recv = __shfl_xor(send, 32, 64);
        o[0] = (up ? o[1] : o[0]) + recv;
    }
    // lane (g,r) now holds the summed output for dim 16r + bitrev4(g)
    const int w = ((g & 1) << 3) | ((g & 2) << 1) | ((g & 4) >> 1) | ((g & 8) >> 3);
    out[(size_t)node * 64 + 16 * r + w] = o[0] / ((w < 8) ? sa : sb);
}

extern "C" void kernel_launch(void* const* d_in, const int* in_sizes, int n_in,
                              void* d_out, int out_size, void* d_ws, size_t ws_size,
                              hipStream_t stream) {
    const float* x = (const float*)d_in[0];
    const float* W = (const float*)d_in[1];
    // d_in[2] = batch (unused by reference)
    const int* ei = (const int*)d_in[3];
    const int* dest = ei + E_EDGES;  // ei[1]
    float* out = (float*)d_out;

    unsigned short* qkv = (unsigned short*)d_ws;                    // 19.2 MB
    unsigned short* Wb  = qkv + (size_t)N_NODES * FTOT;             // +48 KB bf16 W image

    wprep<<<12, 256, 0, stream>>>(W, Wb);
    gemm_qkv<<<(N_NODES + 63) / 64, 256, 0, stream>>>(x, Wb, qkv);
    attn<<<(N_NODES + 3) / 4, 256, 0, stream>>>(qkv, dest, out);
}